// Round 2
// baseline (474.682 us; speedup 1.0000x reference)
//
#include <hip/hip_runtime.h>
#include <cstdint>

#define NN 100000
#define NEG 0.2f

// ---------------- edge dtype detector ----------------
// Reference declares edge_index int64, but without jax x64 it may arrive as
// int32, and the harness doc says "integer -> const int*". Detect at runtime:
// for int64 (values < 2^31) the odd int32 words are all zero; for random
// int32 indices in [0,100000) the chance all 64 odd words are zero is ~1e-320.
__global__ void k_detect(const void* e, int* mode) {
    if (threadIdx.x == 0 && blockIdx.x == 0) {
        const int* p = (const int*)e;
        int allz = 1;
        for (int i = 0; i < 64; ++i)
            if (p[2 * i + 1] != 0) { allz = 0; break; }
        mode[0] = allz;  // 1 => int64, 0 => int32
    }
}

__device__ __forceinline__ void load_edge(const void* e, long E, long i, int is64,
                                          long& s, long& d) {
    if (is64) {
        const long long* p = (const long long*)e;
        s = (long)p[i]; d = (long)p[E + i];
    } else {
        const int* p = (const int*)e;
        s = p[i]; d = p[E + i];
    }
}

// ---------------- CSR build ----------------
__global__ void k_init_cnt(int* cnt, int n) {
    int i = blockIdx.x * 256 + threadIdx.x;
    if (i < n) cnt[i] = 1;  // reserve slot 0 for the self-loop
}

__global__ void k_count(const void* e, long E, const int* mode, int* cnt, int n) {
    long i = (long)blockIdx.x * 256 + threadIdx.x;
    if (i >= E) return;
    int is64 = mode[0];
    long s, d;
    load_edge(e, E, i, is64, s, d);
    if ((unsigned long)s < (unsigned long)n && (unsigned long)d < (unsigned long)n)
        atomicAdd(&cnt[d], 1);
}

// 3-phase exclusive scan of cnt[0..n) -> rowptr[0..n], blocks of 256
__global__ void k_scan_block(const int* cnt, int* excl, int* bsums, int n) {
    __shared__ int sm[256];
    int i = blockIdx.x * 256 + threadIdx.x;
    int v = (i < n) ? cnt[i] : 0;
    sm[threadIdx.x] = v;
    __syncthreads();
    for (int off = 1; off < 256; off <<= 1) {
        int t = (threadIdx.x >= off) ? sm[threadIdx.x - off] : 0;
        __syncthreads();
        sm[threadIdx.x] += t;
        __syncthreads();
    }
    if (i < n) excl[i] = sm[threadIdx.x] - v;
    if (threadIdx.x == 255) bsums[blockIdx.x] = sm[255];
}

__global__ void k_scan_bsums(int* bsums, int nb) {
    __shared__ int sm[512];
    int t = threadIdx.x;
    int v = (t < nb) ? bsums[t] : 0;
    sm[t] = v;
    __syncthreads();
    for (int off = 1; off < 512; off <<= 1) {
        int tv = (t >= off) ? sm[t - off] : 0;
        __syncthreads();
        sm[t] += tv;
        __syncthreads();
    }
    if (t < nb) bsums[t] = sm[t] - v;  // exclusive
}

__global__ void k_scan_add(int* rowptr, const int* bsums, const int* cnt, int n) {
    int i = blockIdx.x * 256 + threadIdx.x;
    if (i < n) {
        int v = rowptr[i] + bsums[blockIdx.x];
        rowptr[i] = v;
        if (i == n - 1) rowptr[n] = v + cnt[i];
    }
}

__global__ void k_fill_self(const int* rowptr, int* csr, int* cursor, int n) {
    int i = blockIdx.x * 256 + threadIdx.x;
    if (i < n) {
        csr[rowptr[i]] = i;  // self-loop at slot 0
        cursor[i] = 1;
    }
}

__global__ void k_fill(const void* e, long E, const int* mode, const int* rowptr,
                       int* cursor, int* csr, int n) {
    long i = (long)blockIdx.x * 256 + threadIdx.x;
    if (i >= E) return;
    int is64 = mode[0];
    long s, d;
    load_edge(e, E, i, is64, s, d);
    if ((unsigned long)s < (unsigned long)n && (unsigned long)d < (unsigned long)n) {
        int slot = atomicAdd(&cursor[d], 1);
        csr[rowptr[d] + slot] = (int)s;
    }
}

// ---------------- register-tiled GEMM + attention dots ----------------
// H = X @ W  ([n,K] x [K,64]); AS[r] = H[r,:]·a_s; AD[r] = H[r,:]·a_d.
// Block = 256 threads = 64 rows x 64 ch tile; thread (ty,tx) owns a 4x4
// register tile. X chunk staged TRANSPOSED in LDS (pad 68 -> aligned b128,
// conflict-free compute reads); W chunk staged contiguously.
template <int K>
__global__ __launch_bounds__(256) void k_gemm_attn(
    const float* __restrict__ X, const float* __restrict__ W,
    const float* __restrict__ As, const float* __restrict__ Ad,
    float* __restrict__ H, float* __restrict__ AS, float* __restrict__ AD, int n) {
    constexpr int KC = 32;
    __shared__ float Wl[KC * 64];   // 8 KB
    __shared__ float Xt[KC][68];    // 8.5 KB, transposed [k][row]
    const int tid = threadIdx.x;
    const int tx = tid & 15, ty = tid >> 4;
    const long row0 = (long)blockIdx.x * 64;
    float acc[4][4] = {{0.f}};

    for (int k0 = 0; k0 < K; k0 += KC) {
        __syncthreads();
        // stage W chunk: contiguous [KC][64]
        {
            const float4* src = (const float4*)(W + (long)k0 * 64);
            float4* dst = (float4*)Wl;
            for (int i = tid; i < KC * 64 / 4; i += 256) dst[i] = src[i];
        }
        // stage X chunk transposed: rows row0..row0+63, k in [k0,k0+KC)
        {
            const int rr = tid >> 3;   // 0..31
            const int kq = tid & 7;    // k sub-offset kq*4
#pragma unroll
            for (int h = 0; h < 2; ++h) {
                int r = rr + h * 32;
                long row = row0 + r;
                if (row >= n) row = n - 1;  // clamp (tail block)
                float4 v = *(const float4*)(X + row * K + k0 + kq * 4);
                Xt[kq * 4 + 0][r] = v.x;
                Xt[kq * 4 + 1][r] = v.y;
                Xt[kq * 4 + 2][r] = v.z;
                Xt[kq * 4 + 3][r] = v.w;
            }
        }
        __syncthreads();
#pragma unroll
        for (int kk = 0; kk < KC; ++kk) {
            float4 xv = *(const float4*)(&Xt[kk][ty * 4]);
            float4 wv = *(const float4*)(&Wl[kk * 64 + tx * 4]);
            acc[0][0] += xv.x * wv.x; acc[0][1] += xv.x * wv.y;
            acc[0][2] += xv.x * wv.z; acc[0][3] += xv.x * wv.w;
            acc[1][0] += xv.y * wv.x; acc[1][1] += xv.y * wv.y;
            acc[1][2] += xv.y * wv.z; acc[1][3] += xv.y * wv.w;
            acc[2][0] += xv.z * wv.x; acc[2][1] += xv.z * wv.y;
            acc[2][2] += xv.z * wv.z; acc[2][3] += xv.z * wv.w;
            acc[3][0] += xv.w * wv.x; acc[3][1] += xv.w * wv.y;
            acc[3][2] += xv.w * wv.z; acc[3][3] += xv.w * wv.w;
        }
    }

    // write H (coalesced float4 per row slice)
#pragma unroll
    for (int i = 0; i < 4; ++i) {
        long row = row0 + ty * 4 + i;
        if (row < n) {
            float4 o = {acc[i][0], acc[i][1], acc[i][2], acc[i][3]};
            *(float4*)(H + row * 64 + tx * 4) = o;
        }
    }
    // attention dots: partial over 4 owned channels, reduce across tx group
    float4 asv = *(const float4*)(As + tx * 4);
    float4 adv = *(const float4*)(Ad + tx * 4);
#pragma unroll
    for (int i = 0; i < 4; ++i) {
        float ps = acc[i][0] * asv.x + acc[i][1] * asv.y + acc[i][2] * asv.z + acc[i][3] * asv.w;
        float pd = acc[i][0] * adv.x + acc[i][1] * adv.y + acc[i][2] * adv.z + acc[i][3] * adv.w;
#pragma unroll
        for (int off = 1; off < 16; off <<= 1) {
            ps += __shfl_xor(ps, off);
            pd += __shfl_xor(pd, off);
        }
        if (tx == 0) {
            long row = row0 + ty * 4 + i;
            if (row < n) { AS[row] = ps; AD[row] = pd; }
        }
    }
}

// ---------------- per-node softmax-aggregate ----------------
// one wave per node; lane = channel in the gather phase.
__global__ __launch_bounds__(256) void k_agg(
    const int* __restrict__ rowptr, const int* __restrict__ csr,
    const float* __restrict__ AS, const float* __restrict__ AD,
    const float* __restrict__ H, const float* __restrict__ B,
    float* __restrict__ OUT, int n, int relu) {
    const int lane = threadIdx.x & 63;
    const int node = blockIdx.x * 4 + (threadIdx.x >> 6);
    if (node >= n) return;
    const int beg = rowptr[node], end = rowptr[node + 1];
    const int deg = end - beg;
    const float ad = AD[node];
    float acc = 0.f;

    if (deg <= 64) {
        // ---- fast path: everything from one lane-parallel tile load ----
        const int idx = beg + lane;
        const bool v = idx < end;
        int s = v ? csr[idx] : 0;
        float a = v ? AS[s] + ad : -__builtin_inff();
        a = (a >= 0.f) ? a : NEG * a;
        float m = a;
#pragma unroll
        for (int off = 32; off; off >>= 1) m = fmaxf(m, __shfl_xor(m, off));
        float ez = v ? __expf(a - m) : 0.f;
        float z = ez;
#pragma unroll
        for (int off = 32; off; off >>= 1) z += __shfl_xor(z, off);
        float wgt = ez * (1.f / (z + 1e-16f));
        // shfl-distributed weighted gather of H rows, 4-way ILP
        int j = 0;
        for (; j + 4 <= deg; j += 4) {
            int s0 = __shfl(s, j), s1 = __shfl(s, j + 1);
            int s2 = __shfl(s, j + 2), s3 = __shfl(s, j + 3);
            float w0 = __shfl(wgt, j), w1 = __shfl(wgt, j + 1);
            float w2 = __shfl(wgt, j + 2), w3 = __shfl(wgt, j + 3);
            float h0 = H[(long)s0 * 64 + lane];
            float h1 = H[(long)s1 * 64 + lane];
            float h2 = H[(long)s2 * 64 + lane];
            float h3 = H[(long)s3 * 64 + lane];
            acc += w0 * h0 + w1 * h1 + w2 * h2 + w3 * h3;
        }
        for (; j < deg; ++j) {
            int sj = __shfl(s, j);
            float wj = __shfl(wgt, j);
            acc += wj * H[(long)sj * 64 + lane];
        }
    } else {
        // ---- general path: online max/sum then re-read tiles ----
        float m = -__builtin_inff(), z = 0.f;
        for (int p0 = beg; p0 < end; p0 += 64) {
            int idx = p0 + lane;
            float a = -__builtin_inff();
            if (idx < end) {
                int s = csr[idx];
                float t = AS[s] + ad;
                a = (t >= 0.f) ? t : NEG * t;
            }
            float cm = a;
#pragma unroll
            for (int off = 32; off; off >>= 1) cm = fmaxf(cm, __shfl_xor(cm, off));
            float mn = fmaxf(m, cm);
            float ez = (idx < end) ? __expf(a - mn) : 0.f;
#pragma unroll
            for (int off = 32; off; off >>= 1) ez += __shfl_xor(ez, off);
            z = (p0 == beg) ? ez : z * __expf(m - mn) + ez;
            m = mn;
        }
        const float invz = 1.f / (z + 1e-16f);
        for (int p0 = beg; p0 < end; p0 += 64) {
            int idx = p0 + lane;
            int s = 0; float wgt = 0.f;
            if (idx < end) {
                s = csr[idx];
                float a = AS[s] + ad;
                a = (a >= 0.f) ? a : NEG * a;
                wgt = __expf(a - m) * invz;
            }
            int cnt = min(64, end - p0);
            for (int j = 0; j < cnt; ++j) {
                int sj = __shfl(s, j);
                float wj = __shfl(wgt, j);
                acc += wj * H[(long)sj * 64 + lane];
            }
        }
    }
    acc += B[lane];
    if (relu) acc = fmaxf(acc, 0.f);
    OUT[(long)node * 64 + lane] = acc;
}

// ---------------- launch ----------------
extern "C" void kernel_launch(void* const* d_in, const int* in_sizes, int n_in,
                              void* d_out, int out_size, void* d_ws, size_t ws_size,
                              hipStream_t stream) {
    const float* x   = (const float*)d_in[0];
    const void*  eix = d_in[1];
    const float* W1  = (const float*)d_in[2];
    const float* as1 = (const float*)d_in[3];
    const float* ad1 = (const float*)d_in[4];
    const float* b1  = (const float*)d_in[5];
    const float* W2  = (const float*)d_in[6];
    const float* as2 = (const float*)d_in[7];
    const float* ad2 = (const float*)d_in[8];
    const float* b2  = (const float*)d_in[9];
    float* out = (float*)d_out;

    const int  n = NN;
    const long E = (long)in_sizes[1] / 2;

    // workspace carve (256B aligned bump allocator)
    char* w = (char*)d_ws;
    size_t off = 0;
    auto alloc = [&](size_t bytes) -> void* {
        void* p = w + off;
        off = (off + bytes + 255) & ~(size_t)255;
        return p;
    };
    int*   mode   = (int*)alloc(4);
    int*   cnt    = (int*)alloc((size_t)n * 4);
    int*   rowptr = (int*)alloc((size_t)(n + 1) * 4);
    int*   cursor = (int*)alloc((size_t)n * 4);
    int*   bsums  = (int*)alloc(512 * 4);
    int*   csr    = (int*)alloc((size_t)(E + n) * 4);
    float* H      = (float*)alloc((size_t)n * 64 * 4);
    float* AS     = (float*)alloc((size_t)n * 4);
    float* AD     = (float*)alloc((size_t)n * 4);

    const int nbN = (n + 255) / 256;        // 391
    const int nbE = (int)((E + 255) / 256);
    const int nbG = (n + 63) / 64;          // 1563 (tail block: 32 rows)

    k_detect<<<1, 64, 0, stream>>>(eix, mode);
    k_init_cnt<<<nbN, 256, 0, stream>>>(cnt, n);
    k_count<<<nbE, 256, 0, stream>>>(eix, E, mode, cnt, n);
    k_scan_block<<<nbN, 256, 0, stream>>>(cnt, rowptr, bsums, n);
    k_scan_bsums<<<1, 512, 0, stream>>>(bsums, nbN);
    k_scan_add<<<nbN, 256, 0, stream>>>(rowptr, bsums, cnt, n);
    k_fill_self<<<nbN, 256, 0, stream>>>(rowptr, csr, cursor, n);
    k_fill<<<nbE, 256, 0, stream>>>(eix, E, mode, rowptr, cursor, csr, n);

    // layer 1: h1 = x@W1 (+attn dots), aggregate + relu -> out (as temp)
    k_gemm_attn<128><<<nbG, 256, 0, stream>>>(x, W1, as1, ad1, H, AS, AD, n);
    k_agg<<<(n + 3) / 4, 256, 0, stream>>>(rowptr, csr, AS, AD, H, b1, out, n, 1);
    // layer 2: h2 = out@W2 (+attn dots), aggregate -> out
    k_gemm_attn<64><<<nbG, 256, 0, stream>>>(out, W2, as2, ad2, H, AS, AD, n);
    k_agg<<<(n + 3) / 4, 256, 0, stream>>>(rowptr, csr, AS, AD, H, b2, out, n, 0);
}

// Round 6
// 463.124 us; speedup vs baseline: 1.0250x; 1.0250x over previous
//
#include <hip/hip_runtime.h>
#include <cstdint>

#define NN 100000
#define NX 8            // CSR partitions (== XCD count; label is blockIdx&7)
#define NEG 0.2f

// ---------------- edge dtype detector ----------------
// Reference declares edge_index int64; harness may deliver int32. For int64
// values < 2^31 the odd int32 words are all zero; for random int32 indices
// in [0,100000) the chance all 64 odd words are zero is ~0.
__global__ void k_detect(const void* e, int* mode) {
    if (threadIdx.x == 0 && blockIdx.x == 0) {
        const int* p = (const int*)e;
        int allz = 1;
        for (int i = 0; i < 64; ++i)
            if (p[2 * i + 1] != 0) { allz = 0; break; }
        mode[0] = allz;  // 1 => int64, 0 => int32
    }
}

// ---------------- partitioned CSR build ----------------
// Partition label x = blockIdx.x & 7: DETERMINISTIC (correctness requires the
// same edge to use the same x in count and fill; HW XCD id may differ across
// launches — Guideline 16). Under round-robin block->XCD dispatch this also
// makes partition x's csr region written by exactly one XCD -> lines become
// fully dirty in that XCD's L2 before write-back (fixes Round-2's 106 MB
// WRITE_SIZE from partial-line scatter).
__global__ void k_zero(int* p, int n) {
    int i = blockIdx.x * 256 + threadIdx.x;
    if (i < n) p[i] = 0;
}

__global__ void k_count(const void* e, long E, const int* mode, int* cnt) {
    long i = (long)blockIdx.x * 256 + threadIdx.x;
    if (i >= E) return;
    const int x = (int)(blockIdx.x & (NX - 1));
    long d;
    if (mode[0]) d = (long)((const long long*)e)[E + i];
    else         d = ((const int*)e)[E + i];
    atomicAdd(&cnt[(long)x * NN + d], 1);
}

// 3-level exclusive scan over NS=8*NN elements: cnt -> S, blocks of 256
__global__ void k_scan_block(const int* cnt, int* S, int* bsums, int n) {
    __shared__ int sm[256];
    int i = blockIdx.x * 256 + threadIdx.x;
    int v = (i < n) ? cnt[i] : 0;
    sm[threadIdx.x] = v;
    __syncthreads();
    for (int off = 1; off < 256; off <<= 1) {
        int t = (threadIdx.x >= off) ? sm[threadIdx.x - off] : 0;
        __syncthreads();
        sm[threadIdx.x] += t;
        __syncthreads();
    }
    if (i < n) S[i] = sm[threadIdx.x] - v;
    if (threadIdx.x == 255) bsums[blockIdx.x] = sm[255];
}

// single block, 1024 threads, multi-round exclusive scan of bsums[nb]
__global__ void k_scan_mid(int* bs, int nb) {
    __shared__ int sm[1024];
    __shared__ int carry_s;
    const int t = threadIdx.x;
    if (t == 0) carry_s = 0;
    __syncthreads();
    for (int r = 0; r * 1024 < nb; ++r) {
        int i = r * 1024 + t;
        int v = (i < nb) ? bs[i] : 0;
        sm[t] = v;
        __syncthreads();
        for (int off = 1; off < 1024; off <<= 1) {
            int tv = (t >= off) ? sm[t - off] : 0;
            __syncthreads();
            sm[t] += tv;
            __syncthreads();
        }
        int carry = carry_s;
        if (i < nb) bs[i] = sm[t] - v + carry;
        __syncthreads();
        if (t == 1023) carry_s = carry + sm[1023];
        __syncthreads();
    }
}

__global__ void k_scan_add(int* S, const int* bsums, int n) {
    int i = blockIdx.x * 256 + threadIdx.x;
    if (i < n) S[i] += bsums[blockIdx.x];
}

// fill: slot = atomicAdd(&S[x*NN+d]) (S holds scanned starts; after this
// kernel S[x*NN+d] == segment END, reused by k_agg).
__global__ void k_fill(const void* e, long E, const int* mode, int* S, int* csr) {
    long i = (long)blockIdx.x * 256 + threadIdx.x;
    if (i >= E) return;
    const int x = (int)(blockIdx.x & (NX - 1));
    long s, d;
    if (mode[0]) {
        const long long* p = (const long long*)e;
        s = (long)p[i]; d = (long)p[E + i];
    } else {
        const int* p = (const int*)e;
        s = p[i]; d = p[E + i];
    }
    int pos = atomicAdd(&S[(long)x * NN + d], 1);
    csr[pos] = (int)s;
}

// ---------------- register-tiled GEMM + attention dots ----------------
// H = X @ W  ([n,K] x [K,64]); AS[r] = H[r,:]·a_s; AD[r] = H[r,:]·a_d.
// Block = 256 threads = 64 rows x 64 ch; thread (ty,tx) owns a 4x4 tile.
template <int K>
__global__ __launch_bounds__(256) void k_gemm_attn(
    const float* __restrict__ X, const float* __restrict__ W,
    const float* __restrict__ As, const float* __restrict__ Ad,
    float* __restrict__ H, float* __restrict__ AS, float* __restrict__ AD, int n) {
    constexpr int KC = 32;
    __shared__ float Wl[KC * 64];   // 8 KB
    __shared__ float Xt[KC][68];    // 8.5 KB, transposed [k][row]
    const int tid = threadIdx.x;
    const int tx = tid & 15, ty = tid >> 4;
    const long row0 = (long)blockIdx.x * 64;
    float acc[4][4] = {{0.f}};

    for (int k0 = 0; k0 < K; k0 += KC) {
        __syncthreads();
        {
            const float4* src = (const float4*)(W + (long)k0 * 64);
            float4* dst = (float4*)Wl;
            for (int i = tid; i < KC * 64 / 4; i += 256) dst[i] = src[i];
        }
        {
            const int rr = tid >> 3;   // 0..31
            const int kq = tid & 7;    // k sub-offset kq*4
#pragma unroll
            for (int h = 0; h < 2; ++h) {
                int r = rr + h * 32;
                long row = row0 + r;
                if (row >= n) row = n - 1;  // clamp (tail block)
                float4 v = *(const float4*)(X + row * K + k0 + kq * 4);
                Xt[kq * 4 + 0][r] = v.x;
                Xt[kq * 4 + 1][r] = v.y;
                Xt[kq * 4 + 2][r] = v.z;
                Xt[kq * 4 + 3][r] = v.w;
            }
        }
        __syncthreads();
#pragma unroll
        for (int kk = 0; kk < KC; ++kk) {
            float4 xv = *(const float4*)(&Xt[kk][ty * 4]);
            float4 wv = *(const float4*)(&Wl[kk * 64 + tx * 4]);
            acc[0][0] += xv.x * wv.x; acc[0][1] += xv.x * wv.y;
            acc[0][2] += xv.x * wv.z; acc[0][3] += xv.x * wv.w;
            acc[1][0] += xv.y * wv.x; acc[1][1] += xv.y * wv.y;
            acc[1][2] += xv.y * wv.z; acc[1][3] += xv.y * wv.w;
            acc[2][0] += xv.z * wv.x; acc[2][1] += xv.z * wv.y;
            acc[2][2] += xv.z * wv.z; acc[2][3] += xv.z * wv.w;
            acc[3][0] += xv.w * wv.x; acc[3][1] += xv.w * wv.y;
            acc[3][2] += xv.w * wv.z; acc[3][3] += xv.w * wv.w;
        }
    }

#pragma unroll
    for (int i = 0; i < 4; ++i) {
        long row = row0 + ty * 4 + i;
        if (row < n) {
            float4 o = {acc[i][0], acc[i][1], acc[i][2], acc[i][3]};
            *(float4*)(H + row * 64 + tx * 4) = o;
        }
    }
    float4 asv = *(const float4*)(As + tx * 4);
    float4 adv = *(const float4*)(Ad + tx * 4);
#pragma unroll
    for (int i = 0; i < 4; ++i) {
        float ps = acc[i][0] * asv.x + acc[i][1] * asv.y + acc[i][2] * asv.z + acc[i][3] * asv.w;
        float pd = acc[i][0] * adv.x + acc[i][1] * adv.y + acc[i][2] * adv.z + acc[i][3] * adv.w;
#pragma unroll
        for (int off = 1; off < 16; off <<= 1) {
            ps += __shfl_xor(ps, off);
            pd += __shfl_xor(pd, off);
        }
        if (tx == 0) {
            long row = row0 + ty * 4 + i;
            if (row < n) { AS[row] = ps; AD[row] = pd; }
        }
    }
}

// ---------------- per-node softmax-aggregate (8-segment CSR) ----------------
// one wave per node; lane = channel in the gather phase. Edge-index space:
// e in [0, degI) maps into the 8 partition segments; e == degI is the
// self-loop (src = node).
__global__ __launch_bounds__(256) void k_agg(
    const int* __restrict__ cnt, const int* __restrict__ S,  // S = segment ENDs
    const int* __restrict__ csr,
    const float* __restrict__ AS, const float* __restrict__ AD,
    const float* __restrict__ H, const float* __restrict__ B,
    float* __restrict__ OUT, int n, int relu) {
    const int lane = threadIdx.x & 63;
    const int node = blockIdx.x * 4 + (threadIdx.x >> 6);
    if (node >= n) return;

    int cx[NX], sx[NX];
#pragma unroll
    for (int x = 0; x < NX; ++x) {
        int c = cnt[x * NN + node];
        int en = S[x * NN + node];
        cx[x] = c;
        sx[x] = en - c;  // segment start
    }
    int degI = 0;
#pragma unroll
    for (int x = 0; x < NX; ++x) degI += cx[x];
    const int degT = degI + 1;  // + self-loop
    const float ad = AD[node];

    auto lookup = [&](int e) -> int {
        if (e >= degI) return node;  // self (or padding lane; value unused)
        int addr = 0, cum = 0;
#pragma unroll
        for (int x = 0; x < NX; ++x) {
            int o = e - cum;
            if (o >= 0 && o < cx[x]) addr = sx[x] + o;
            cum += cx[x];
        }
        return csr[addr];
    };

    float acc = 0.f;
    if (degT <= 64) {
        // ---- fast path: one lane-parallel tile ----
        const bool v = lane < degT;
        int s = lookup(lane);
        float a = v ? AS[s] + ad : -__builtin_inff();
        a = (a >= 0.f) ? a : NEG * a;
        float m = a;
#pragma unroll
        for (int off = 32; off; off >>= 1) m = fmaxf(m, __shfl_xor(m, off));
        float ez = v ? __expf(a - m) : 0.f;
        float z = ez;
#pragma unroll
        for (int off = 32; off; off >>= 1) z += __shfl_xor(z, off);
        float wgt = ez * (1.f / (z + 1e-16f));
        int j = 0;
        for (; j + 4 <= degT; j += 4) {
            int s0 = __shfl(s, j), s1 = __shfl(s, j + 1);
            int s2 = __shfl(s, j + 2), s3 = __shfl(s, j + 3);
            float w0 = __shfl(wgt, j), w1 = __shfl(wgt, j + 1);
            float w2 = __shfl(wgt, j + 2), w3 = __shfl(wgt, j + 3);
            float h0 = H[(long)s0 * 64 + lane];
            float h1 = H[(long)s1 * 64 + lane];
            float h2 = H[(long)s2 * 64 + lane];
            float h3 = H[(long)s3 * 64 + lane];
            acc += w0 * h0 + w1 * h1 + w2 * h2 + w3 * h3;
        }
        for (; j < degT; ++j) {
            int sj = __shfl(s, j);
            float wj = __shfl(wgt, j);
            acc += wj * H[(long)sj * 64 + lane];
        }
    } else {
        // ---- general path (deg > 63; essentially never at Poisson(16)) ----
        float m = -__builtin_inff(), z = 0.f;
        for (int p0 = 0; p0 < degT; p0 += 64) {
            int e = p0 + lane;
            bool v = e < degT;
            int s = lookup(e);
            float a = v ? AS[s] + ad : -__builtin_inff();
            a = (a >= 0.f) ? a : NEG * a;
            float cm = a;
#pragma unroll
            for (int off = 32; off; off >>= 1) cm = fmaxf(cm, __shfl_xor(cm, off));
            float mn = fmaxf(m, cm);
            float ez = v ? __expf(a - mn) : 0.f;
#pragma unroll
            for (int off = 32; off; off >>= 1) ez += __shfl_xor(ez, off);
            z = (p0 == 0) ? ez : z * __expf(m - mn) + ez;
            m = mn;
        }
        const float invz = 1.f / (z + 1e-16f);
        for (int p0 = 0; p0 < degT; p0 += 64) {
            int e = p0 + lane;
            bool v = e < degT;
            int s = lookup(e);
            float wgt = 0.f;
            if (v) {
                float a = AS[s] + ad;
                a = (a >= 0.f) ? a : NEG * a;
                wgt = __expf(a - m) * invz;
            }
            int cntv = min(64, degT - p0);
            for (int j = 0; j < cntv; ++j) {
                int sj = __shfl(s, j);
                float wj = __shfl(wgt, j);
                acc += wj * H[(long)sj * 64 + lane];
            }
        }
    }
    acc += B[lane];
    if (relu) acc = fmaxf(acc, 0.f);
    OUT[(long)node * 64 + lane] = acc;
}

// ---------------- launch ----------------
extern "C" void kernel_launch(void* const* d_in, const int* in_sizes, int n_in,
                              void* d_out, int out_size, void* d_ws, size_t ws_size,
                              hipStream_t stream) {
    const float* x   = (const float*)d_in[0];
    const void*  eix = d_in[1];
    const float* W1  = (const float*)d_in[2];
    const float* as1 = (const float*)d_in[3];
    const float* ad1 = (const float*)d_in[4];
    const float* b1  = (const float*)d_in[5];
    const float* W2  = (const float*)d_in[6];
    const float* as2 = (const float*)d_in[7];
    const float* ad2 = (const float*)d_in[8];
    const float* b2  = (const float*)d_in[9];
    float* out = (float*)d_out;

    const int  n  = NN;
    const long E  = (long)in_sizes[1] / 2;
    const int  NS = NX * NN;  // 800000

    // workspace carve (256B aligned bump allocator)
    char* w = (char*)d_ws;
    size_t off = 0;
    auto alloc = [&](size_t bytes) -> void* {
        void* p = w + off;
        off = (off + bytes + 255) & ~(size_t)255;
        return p;
    };
    int*   mode  = (int*)alloc(4);
    int*   cnt   = (int*)alloc((size_t)NS * 4);
    int*   S     = (int*)alloc((size_t)NS * 4);
    int*   bsums = (int*)alloc(4096 * 4);
    int*   csr   = (int*)alloc((size_t)E * 4);
    float* H     = (float*)alloc((size_t)n * 64 * 4);
    float* AS    = (float*)alloc((size_t)n * 4);
    float* AD    = (float*)alloc((size_t)n * 4);

    const int nbS = (NS + 255) / 256;        // 3125
    const int nbE = (int)((E + 255) / 256);  // 6250
    const int nbG = (n + 63) / 64;           // 1563

    k_detect<<<1, 64, 0, stream>>>(eix, mode);
    k_zero<<<nbS, 256, 0, stream>>>(cnt, NS);
    k_count<<<nbE, 256, 0, stream>>>(eix, E, mode, cnt);
    k_scan_block<<<nbS, 256, 0, stream>>>(cnt, S, bsums, NS);
    k_scan_mid<<<1, 1024, 0, stream>>>(bsums, nbS);
    k_scan_add<<<nbS, 256, 0, stream>>>(S, bsums, NS);
    k_fill<<<nbE, 256, 0, stream>>>(eix, E, mode, S, csr);

    // layer 1: h1 = x@W1 (+attn dots), aggregate + relu -> out (as temp)
    k_gemm_attn<128><<<nbG, 256, 0, stream>>>(x, W1, as1, ad1, H, AS, AD, n);
    k_agg<<<(n + 3) / 4, 256, 0, stream>>>(cnt, S, csr, AS, AD, H, b1, out, n, 1);
    // layer 2: h2 = out@W2 (+attn dots), aggregate -> out
    k_gemm_attn<64><<<nbG, 256, 0, stream>>>(out, W2, as2, ad2, H, AS, AD, n);
    k_agg<<<(n + 3) / 4, 256, 0, stream>>>(cnt, S, csr, AS, AD, H, b2, out, n, 0);
}

// Round 8
// 461.208 us; speedup vs baseline: 1.0292x; 1.0042x over previous
//
#include <hip/hip_runtime.h>
#include <cstdint>

#define NN 100000
#define NX 8            // CSR partitions (label = blockIdx&7 for fill locality)
#define NEG 0.2f

// ---------------- edge dtype detector ----------------
__global__ void k_detect(const void* e, int* mode) {
    if (threadIdx.x == 0 && blockIdx.x == 0) {
        const int* p = (const int*)e;
        int allz = 1;
        for (int i = 0; i < 64; ++i)
            if (p[2 * i + 1] != 0) { allz = 0; break; }
        mode[0] = allz;  // 1 => int64, 0 => int32
    }
}

// ---------------- partitioned CSR build ----------------
// x-major layout cnt[x*NN+d]: partition x's csr region is written only by
// blocks with label x (= same XCD under round-robin dispatch) -> full-line
// write-combining (fixed Round-2's 106 MB WRITE_SIZE).
__global__ void k_zero(int* p, int n) {
    int i = blockIdx.x * 256 + threadIdx.x;
    if (i < n) p[i] = 0;
}

__global__ void k_count(const void* e, long E, const int* mode, int* cnt) {
    long i = (long)blockIdx.x * 256 + threadIdx.x;
    if (i >= E) return;
    const int x = (int)(blockIdx.x & (NX - 1));
    long d;
    if (mode[0]) d = (long)((const long long*)e)[E + i];
    else         d = ((const int*)e)[E + i];
    atomicAdd(&cnt[(long)x * NN + d], 1);
}

// 3-level exclusive scan over NS=8*NN elements: cnt -> S
__global__ void k_scan_block(const int* cnt, int* S, int* bsums, int n) {
    __shared__ int sm[256];
    int i = blockIdx.x * 256 + threadIdx.x;
    int v = (i < n) ? cnt[i] : 0;
    sm[threadIdx.x] = v;
    __syncthreads();
    for (int off = 1; off < 256; off <<= 1) {
        int t = (threadIdx.x >= off) ? sm[threadIdx.x - off] : 0;
        __syncthreads();
        sm[threadIdx.x] += t;
        __syncthreads();
    }
    if (i < n) S[i] = sm[threadIdx.x] - v;
    if (threadIdx.x == 255) bsums[blockIdx.x] = sm[255];
}

__global__ void k_scan_mid(int* bs, int nb) {
    __shared__ int sm[1024];
    __shared__ int carry_s;
    const int t = threadIdx.x;
    if (t == 0) carry_s = 0;
    __syncthreads();
    for (int r = 0; r * 1024 < nb; ++r) {
        int i = r * 1024 + t;
        int v = (i < nb) ? bs[i] : 0;
        sm[t] = v;
        __syncthreads();
        for (int off = 1; off < 1024; off <<= 1) {
            int tv = (t >= off) ? sm[t - off] : 0;
            __syncthreads();
            sm[t] += tv;
            __syncthreads();
        }
        int carry = carry_s;
        if (i < nb) bs[i] = sm[t] - v + carry;
        __syncthreads();
        if (t == 1023) carry_s = carry + sm[1023];
        __syncthreads();
    }
}

__global__ void k_scan_add(int* S, const int* bsums, int n) {
    int i = blockIdx.x * 256 + threadIdx.x;
    if (i < n) S[i] += bsums[blockIdx.x];
}

// fill: pos = atomicAdd(&S[x*NN+d]) — S mutates from segment START to END.
// Pristine start is recovered later as S_end - cnt.
__global__ void k_fill(const void* e, long E, const int* mode, int* S, int* csr) {
    long i = (long)blockIdx.x * 256 + threadIdx.x;
    if (i >= E) return;
    const int x = (int)(blockIdx.x & (NX - 1));
    long s, d;
    if (mode[0]) {
        const long long* p = (const long long*)e;
        s = (long)p[i]; d = (long)p[E + i];
    } else {
        const int* p = (const int*)e;
        s = p[i]; d = p[E + i];
    }
    int pos = atomicAdd(&S[(long)x * NN + d], 1);
    csr[pos] = (int)s;
}

// ---------------- reorder: x-major csr -> node-contiguous csr2 ----------------
// Thread per node d: 8-way merge of its partition segments into one contiguous
// run. rowptr2[d] = sum_x start_x(d) - sum_x start_x(0)  (pristine starts =
// S_end - cnt), derived without a second scan. Reads stream sequentially per
// partition across consecutive threads; writes stream contiguously.
__global__ void k_reorder(const int* cnt, const int* Send, const int* csr,
                          int* csr2, int* rowptr2, long E, int n) {
    int d = blockIdx.x * 256 + threadIdx.x;
    if (d >= n) return;
    int C = 0, sum = 0;
    int st[NX], cx[NX];
#pragma unroll
    for (int x = 0; x < NX; ++x) {
        int c0 = cnt[(long)x * NN];
        int e0 = Send[(long)x * NN];
        C += e0 - c0;                       // pristine start at d=0
        int c = cnt[(long)x * NN + d];
        int en = Send[(long)x * NN + d];
        cx[x] = c;
        st[x] = en - c;                     // pristine start at d
        sum += en - c;
    }
    int start = sum - C;
    rowptr2[d] = start;
    if (d == 0) rowptr2[n] = (int)E;
#pragma unroll
    for (int x = 0; x < NX; ++x) {
        int c = cx[x], s0 = st[x];
        for (int j = 0; j < c; ++j) csr2[start++] = csr[s0 + j];
    }
}

// ---------------- register-tiled GEMM + attention dots ----------------
template <int K>
__global__ __launch_bounds__(256) void k_gemm_attn(
    const float* __restrict__ X, const float* __restrict__ W,
    const float* __restrict__ As, const float* __restrict__ Ad,
    float* __restrict__ H, float* __restrict__ AS, float* __restrict__ AD, int n) {
    constexpr int KC = 32;
    __shared__ float Wl[KC * 64];   // 8 KB
    __shared__ float Xt[KC][68];    // 8.5 KB, transposed [k][row]
    const int tid = threadIdx.x;
    const int tx = tid & 15, ty = tid >> 4;
    const long row0 = (long)blockIdx.x * 64;
    float acc[4][4] = {{0.f}};

    for (int k0 = 0; k0 < K; k0 += KC) {
        __syncthreads();
        {
            const float4* src = (const float4*)(W + (long)k0 * 64);
            float4* dst = (float4*)Wl;
            for (int i = tid; i < KC * 64 / 4; i += 256) dst[i] = src[i];
        }
        {
            const int rr = tid >> 3;   // 0..31
            const int kq = tid & 7;    // k sub-offset kq*4
#pragma unroll
            for (int h = 0; h < 2; ++h) {
                int r = rr + h * 32;
                long row = row0 + r;
                if (row >= n) row = n - 1;
                float4 v = *(const float4*)(X + row * K + k0 + kq * 4);
                Xt[kq * 4 + 0][r] = v.x;
                Xt[kq * 4 + 1][r] = v.y;
                Xt[kq * 4 + 2][r] = v.z;
                Xt[kq * 4 + 3][r] = v.w;
            }
        }
        __syncthreads();
#pragma unroll
        for (int kk = 0; kk < KC; ++kk) {
            float4 xv = *(const float4*)(&Xt[kk][ty * 4]);
            float4 wv = *(const float4*)(&Wl[kk * 64 + tx * 4]);
            acc[0][0] += xv.x * wv.x; acc[0][1] += xv.x * wv.y;
            acc[0][2] += xv.x * wv.z; acc[0][3] += xv.x * wv.w;
            acc[1][0] += xv.y * wv.x; acc[1][1] += xv.y * wv.y;
            acc[1][2] += xv.y * wv.z; acc[1][3] += xv.y * wv.w;
            acc[2][0] += xv.z * wv.x; acc[2][1] += xv.z * wv.y;
            acc[2][2] += xv.z * wv.z; acc[2][3] += xv.z * wv.w;
            acc[3][0] += xv.w * wv.x; acc[3][1] += xv.w * wv.y;
            acc[3][2] += xv.w * wv.z; acc[3][3] += xv.w * wv.w;
        }
    }

#pragma unroll
    for (int i = 0; i < 4; ++i) {
        long row = row0 + ty * 4 + i;
        if (row < n) {
            float4 o = {acc[i][0], acc[i][1], acc[i][2], acc[i][3]};
            *(float4*)(H + row * 64 + tx * 4) = o;
        }
    }
    float4 asv = *(const float4*)(As + tx * 4);
    float4 adv = *(const float4*)(Ad + tx * 4);
#pragma unroll
    for (int i = 0; i < 4; ++i) {
        float ps = acc[i][0] * asv.x + acc[i][1] * asv.y + acc[i][2] * asv.z + acc[i][3] * asv.w;
        float pd = acc[i][0] * adv.x + acc[i][1] * adv.y + acc[i][2] * adv.z + acc[i][3] * adv.w;
#pragma unroll
        for (int off = 1; off < 16; off <<= 1) {
            ps += __shfl_xor(ps, off);
            pd += __shfl_xor(pd, off);
        }
        if (tx == 0) {
            long row = row0 + ty * 4 + i;
            if (row < n) { AS[row] = ps; AD[row] = pd; }
        }
    }
}

// ---------------- per-node softmax-aggregate (contiguous CSR) ----------------
// one wave per node; lane = channel in the gather phase; edge degI == self.
__global__ __launch_bounds__(256) void k_agg(
    const int* __restrict__ rowptr, const int* __restrict__ csr,
    const float* __restrict__ AS, const float* __restrict__ AD,
    const float* __restrict__ H, const float* __restrict__ B,
    float* __restrict__ OUT, int n, int relu) {
    const int lane = threadIdx.x & 63;
    const int node = blockIdx.x * 4 + (threadIdx.x >> 6);
    if (node >= n) return;
    const int beg = rowptr[node], end = rowptr[node + 1];
    const int degI = end - beg;
    const int degT = degI + 1;  // + self-loop
    const float ad = AD[node];

    float acc = 0.f;
    if (degT <= 64) {
        // ---- fast path: one lane-parallel tile ----
        const bool v = lane < degT;
        int s = (lane < degI) ? csr[beg + lane] : node;
        float a = v ? AS[s] + ad : -__builtin_inff();
        a = (a >= 0.f) ? a : NEG * a;
        float m = a;
#pragma unroll
        for (int off = 32; off; off >>= 1) m = fmaxf(m, __shfl_xor(m, off));
        float ez = v ? __expf(a - m) : 0.f;
        float z = ez;
#pragma unroll
        for (int off = 32; off; off >>= 1) z += __shfl_xor(z, off);
        float wgt = ez * (1.f / (z + 1e-16f));
        // shfl-distributed weighted gather of H rows, 8-way ILP
        int j = 0;
        for (; j + 8 <= degT; j += 8) {
            int s0 = __shfl(s, j),     s1 = __shfl(s, j + 1);
            int s2 = __shfl(s, j + 2), s3 = __shfl(s, j + 3);
            int s4 = __shfl(s, j + 4), s5 = __shfl(s, j + 5);
            int s6 = __shfl(s, j + 6), s7 = __shfl(s, j + 7);
            float w0 = __shfl(wgt, j),     w1 = __shfl(wgt, j + 1);
            float w2 = __shfl(wgt, j + 2), w3 = __shfl(wgt, j + 3);
            float w4 = __shfl(wgt, j + 4), w5 = __shfl(wgt, j + 5);
            float w6 = __shfl(wgt, j + 6), w7 = __shfl(wgt, j + 7);
            float h0 = H[(long)s0 * 64 + lane];
            float h1 = H[(long)s1 * 64 + lane];
            float h2 = H[(long)s2 * 64 + lane];
            float h3 = H[(long)s3 * 64 + lane];
            float h4 = H[(long)s4 * 64 + lane];
            float h5 = H[(long)s5 * 64 + lane];
            float h6 = H[(long)s6 * 64 + lane];
            float h7 = H[(long)s7 * 64 + lane];
            acc += w0 * h0 + w1 * h1 + w2 * h2 + w3 * h3;
            acc += w4 * h4 + w5 * h5 + w6 * h6 + w7 * h7;
        }
        for (; j < degT; ++j) {
            int sj = __shfl(s, j);
            float wj = __shfl(wgt, j);
            acc += wj * H[(long)sj * 64 + lane];
        }
    } else {
        // ---- general path (degT > 64; absent at Poisson(16), kept for safety)
        float m = -__builtin_inff(), z = 0.f;
        for (int p0 = 0; p0 < degT; p0 += 64) {
            int e = p0 + lane;
            bool v = e < degT;
            int s = (e < degI) ? csr[beg + e] : node;
            float a = v ? AS[s] + ad : -__builtin_inff();
            a = (a >= 0.f) ? a : NEG * a;
            float cm = a;
#pragma unroll
            for (int off = 32; off; off >>= 1) cm = fmaxf(cm, __shfl_xor(cm, off));
            float mn = fmaxf(m, cm);
            float ez = v ? __expf(a - mn) : 0.f;
#pragma unroll
            for (int off = 32; off; off >>= 1) ez += __shfl_xor(ez, off);
            z = (p0 == 0) ? ez : z * __expf(m - mn) + ez;
            m = mn;
        }
        const float invz = 1.f / (z + 1e-16f);
        for (int p0 = 0; p0 < degT; p0 += 64) {
            int e = p0 + lane;
            bool v = e < degT;
            int s = (e < degI) ? csr[beg + e] : node;
            float wgt = 0.f;
            if (v) {
                float a = AS[s] + ad;
                a = (a >= 0.f) ? a : NEG * a;
                wgt = __expf(a - m) * invz;
            }
            int cntv = min(64, degT - p0);
            for (int j = 0; j < cntv; ++j) {
                int sj = __shfl(s, j);
                float wj = __shfl(wgt, j);
                acc += wj * H[(long)sj * 64 + lane];
            }
        }
    }
    acc += B[lane];
    if (relu) acc = fmaxf(acc, 0.f);
    OUT[(long)node * 64 + lane] = acc;
}

// ---------------- launch ----------------
extern "C" void kernel_launch(void* const* d_in, const int* in_sizes, int n_in,
                              void* d_out, int out_size, void* d_ws, size_t ws_size,
                              hipStream_t stream) {
    const float* x   = (const float*)d_in[0];
    const void*  eix = d_in[1];
    const float* W1  = (const float*)d_in[2];
    const float* as1 = (const float*)d_in[3];
    const float* ad1 = (const float*)d_in[4];
    const float* b1  = (const float*)d_in[5];
    const float* W2  = (const float*)d_in[6];
    const float* as2 = (const float*)d_in[7];
    const float* ad2 = (const float*)d_in[8];
    const float* b2  = (const float*)d_in[9];
    float* out = (float*)d_out;

    const int  n  = NN;
    const long E  = (long)in_sizes[1] / 2;
    const int  NS = NX * NN;  // 800000

    // workspace carve (256B aligned bump allocator), ~46 MB total
    char* w = (char*)d_ws;
    size_t off = 0;
    auto alloc = [&](size_t bytes) -> void* {
        void* p = w + off;
        off = (off + bytes + 255) & ~(size_t)255;
        return p;
    };
    int*   mode    = (int*)alloc(4);
    int*   cnt     = (int*)alloc((size_t)NS * 4);
    int*   S       = (int*)alloc((size_t)NS * 4);
    int*   bsums   = (int*)alloc(4096 * 4);
    int*   csr     = (int*)alloc((size_t)E * 4);
    int*   csr2    = (int*)alloc((size_t)E * 4);
    int*   rowptr2 = (int*)alloc((size_t)(n + 1) * 4);
    float* H       = (float*)alloc((size_t)n * 64 * 4);
    float* AS      = (float*)alloc((size_t)n * 4);
    float* AD      = (float*)alloc((size_t)n * 4);

    const int nbS = (NS + 255) / 256;        // 3125
    const int nbE = (int)((E + 255) / 256);  // 6250
    const int nbN = (n + 255) / 256;         // 391
    const int nbG = (n + 63) / 64;           // 1563

    k_detect<<<1, 64, 0, stream>>>(eix, mode);
    k_zero<<<nbS, 256, 0, stream>>>(cnt, NS);
    k_count<<<nbE, 256, 0, stream>>>(eix, E, mode, cnt);
    k_scan_block<<<nbS, 256, 0, stream>>>(cnt, S, bsums, NS);
    k_scan_mid<<<1, 1024, 0, stream>>>(bsums, nbS);
    k_scan_add<<<nbS, 256, 0, stream>>>(S, bsums, NS);
    k_fill<<<nbE, 256, 0, stream>>>(eix, E, mode, S, csr);   // S: starts -> ends
    k_reorder<<<nbN, 256, 0, stream>>>(cnt, S, csr, csr2, rowptr2, E, n);

    // layer 1: h1 = x@W1 (+attn dots), aggregate + relu -> out (as temp)
    k_gemm_attn<128><<<nbG, 256, 0, stream>>>(x, W1, as1, ad1, H, AS, AD, n);
    k_agg<<<(n + 3) / 4, 256, 0, stream>>>(rowptr2, csr2, AS, AD, H, b1, out, n, 1);
    // layer 2: h2 = out@W2 (+attn dots), aggregate -> out
    k_gemm_attn<64><<<nbG, 256, 0, stream>>>(out, W2, as2, ad2, H, AS, AD, n);
    k_agg<<<(n + 3) / 4, 256, 0, stream>>>(rowptr2, csr2, AS, AD, H, b2, out, n, 0);
}

// Round 10
// 399.267 us; speedup vs baseline: 1.1889x; 1.1551x over previous
//
#include <hip/hip_runtime.h>
#include <cstdint>

#define NN 100000
#define NX 8            // CSR partitions (label = blockIdx&7 for fill locality)
#define NEG 0.2f

// ---------------- zero + edge dtype detector (fused) ----------------
__global__ void k_zero_detect(int* p, int n, const void* e, int* mode) {
    int i = blockIdx.x * 256 + threadIdx.x;
    if (i < n) p[i] = 0;
    if (blockIdx.x == 0 && threadIdx.x == 0) {
        const int* q = (const int*)e;
        int allz = 1;
        for (int j = 0; j < 64; ++j)
            if (q[2 * j + 1] != 0) { allz = 0; break; }
        mode[0] = allz;  // 1 => int64, 0 => int32
    }
}

// ---------------- partitioned CSR build ----------------
// x-major cnt[x*NN+d]; partition x's csr region written only by blocks with
// label x (same XCD under round-robin dispatch) -> full-line write-combining.
// count: atomicAdd returns this edge's RANK within cell (x,d); persist
// combo[e] = (rank<<17)|d so k_fill needs NO atomics and no dst re-read.
__global__ void k_count(const void* e, long E, const int* mode, int* cnt,
                        unsigned* combo) {
    long i0 = ((long)blockIdx.x * 256 + threadIdx.x) * 2;
    if (i0 >= E) return;
    const int x = (int)(blockIdx.x & (NX - 1));
    const bool has1 = (i0 + 1) < E;
    int d0, d1 = 0;
    if (mode[0]) {
        const long long* p = (const long long*)e;
        d0 = (int)p[E + i0];
        if (has1) d1 = (int)p[E + i0 + 1];
    } else {
        const int* p = (const int*)e;
        d0 = p[E + i0];
        if (has1) d1 = p[E + i0 + 1];
    }
    int r0 = atomicAdd(&cnt[x * NN + d0], 1);
    combo[i0] = ((unsigned)r0 << 17) | (unsigned)d0;
    if (has1) {
        int r1 = atomicAdd(&cnt[x * NN + d1], 1);
        combo[i0 + 1] = ((unsigned)r1 << 17) | (unsigned)d1;
    }
}

// 3-level exclusive scan over NS=8*NN: level-1 blocks of 1024 -> 782 bsums,
// single-round mid (782 <= 1024), add-back.
__global__ void k_scan_block(const int* cnt, int* S, int* bsums, int n) {
    __shared__ int sm[1024];
    const int t = threadIdx.x;
    int i = blockIdx.x * 1024 + t;
    int v = (i < n) ? cnt[i] : 0;
    sm[t] = v;
    __syncthreads();
    for (int off = 1; off < 1024; off <<= 1) {
        int tv = (t >= off) ? sm[t - off] : 0;
        __syncthreads();
        sm[t] += tv;
        __syncthreads();
    }
    if (i < n) S[i] = sm[t] - v;
    if (t == 1023) bsums[blockIdx.x] = sm[1023];
}

__global__ void k_scan_mid(int* bs, int nb) {
    __shared__ int sm[1024];
    const int t = threadIdx.x;
    int v = (t < nb) ? bs[t] : 0;
    sm[t] = v;
    __syncthreads();
    for (int off = 1; off < 1024; off <<= 1) {
        int tv = (t >= off) ? sm[t - off] : 0;
        __syncthreads();
        sm[t] += tv;
        __syncthreads();
    }
    if (t < nb) bs[t] = sm[t] - v;  // exclusive
}

__global__ void k_scan_add(int* S, const int* bsums, int n) {
    int i = blockIdx.x * 1024 + threadIdx.x;
    if (i < n) S[i] += bsums[blockIdx.x];
}

// fill: slot = S[x*NN+d] + rank (from combo) — NO atomics. S stays pristine.
// Same grid/label mapping as k_count so each edge's x matches its rank's cell.
__global__ void k_fill(const void* e, long E, const int* mode, const int* S,
                       const unsigned* combo, int* csr) {
    long i0 = ((long)blockIdx.x * 256 + threadIdx.x) * 2;
    if (i0 >= E) return;
    const int x = (int)(blockIdx.x & (NX - 1));
    const bool has1 = (i0 + 1) < E;
    long s0, s1 = 0;
    if (mode[0]) {
        const long long* p = (const long long*)e;
        s0 = p[i0];
        if (has1) s1 = p[i0 + 1];
    } else {
        const int* p = (const int*)e;
        s0 = p[i0];
        if (has1) s1 = p[i0 + 1];
    }
    unsigned c0 = combo[i0];
    int d0 = (int)(c0 & 0x1FFFFu), r0 = (int)(c0 >> 17);
    csr[S[x * NN + d0] + r0] = (int)s0;
    if (has1) {
        unsigned c1 = combo[i0 + 1];
        int d1 = (int)(c1 & 0x1FFFFu), r1 = (int)(c1 >> 17);
        csr[S[x * NN + d1] + r1] = (int)s1;
    }
}

// ---------------- reorder: x-major csr -> node-contiguous csr2 ----------------
// S is pristine (fill no longer mutates it): st[x] = S[x*NN+d];
// rowptr2[d] = sum_x S[x*NN+d] - sum_x S[x*NN+0].
__global__ void k_reorder(const int* cnt, const int* S, const int* csr,
                          int* csr2, int* rowptr2, long E, int n) {
    int d = blockIdx.x * 256 + threadIdx.x;
    if (d >= n) return;
    int C = 0, sum = 0;
    int st[NX], cx[NX];
#pragma unroll
    for (int x = 0; x < NX; ++x) {
        C += S[(long)x * NN];
        st[x] = S[(long)x * NN + d];
        cx[x] = cnt[(long)x * NN + d];
        sum += st[x];
    }
    int start = sum - C;
    rowptr2[d] = start;
    if (d == 0) rowptr2[n] = (int)E;
#pragma unroll
    for (int x = 0; x < NX; ++x) {
        int c = cx[x], s0 = st[x];
        for (int j = 0; j < c; ++j) csr2[start++] = csr[s0 + j];
    }
}

// ---------------- register-tiled GEMM + attention dots ----------------
template <int K>
__global__ __launch_bounds__(256) void k_gemm_attn(
    const float* __restrict__ X, const float* __restrict__ W,
    const float* __restrict__ As, const float* __restrict__ Ad,
    float* __restrict__ H, float* __restrict__ AS, float* __restrict__ AD, int n) {
    constexpr int KC = 32;
    __shared__ float Wl[KC * 64];   // 8 KB
    __shared__ float Xt[KC][68];    // 8.5 KB, transposed [k][row]
    const int tid = threadIdx.x;
    const int tx = tid & 15, ty = tid >> 4;
    const long row0 = (long)blockIdx.x * 64;
    float acc[4][4] = {{0.f}};

    for (int k0 = 0; k0 < K; k0 += KC) {
        __syncthreads();
        {
            const float4* src = (const float4*)(W + (long)k0 * 64);
            float4* dst = (float4*)Wl;
            for (int i = tid; i < KC * 64 / 4; i += 256) dst[i] = src[i];
        }
        {
            const int rr = tid >> 3;   // 0..31
            const int kq = tid & 7;    // k sub-offset kq*4
#pragma unroll
            for (int h = 0; h < 2; ++h) {
                int r = rr + h * 32;
                long row = row0 + r;
                if (row >= n) row = n - 1;
                float4 v = *(const float4*)(X + row * K + k0 + kq * 4);
                Xt[kq * 4 + 0][r] = v.x;
                Xt[kq * 4 + 1][r] = v.y;
                Xt[kq * 4 + 2][r] = v.z;
                Xt[kq * 4 + 3][r] = v.w;
            }
        }
        __syncthreads();
#pragma unroll
        for (int kk = 0; kk < KC; ++kk) {
            float4 xv = *(const float4*)(&Xt[kk][ty * 4]);
            float4 wv = *(const float4*)(&Wl[kk * 64 + tx * 4]);
            acc[0][0] += xv.x * wv.x; acc[0][1] += xv.x * wv.y;
            acc[0][2] += xv.x * wv.z; acc[0][3] += xv.x * wv.w;
            acc[1][0] += xv.y * wv.x; acc[1][1] += xv.y * wv.y;
            acc[1][2] += xv.y * wv.z; acc[1][3] += xv.y * wv.w;
            acc[2][0] += xv.z * wv.x; acc[2][1] += xv.z * wv.y;
            acc[2][2] += xv.z * wv.z; acc[2][3] += xv.z * wv.w;
            acc[3][0] += xv.w * wv.x; acc[3][1] += xv.w * wv.y;
            acc[3][2] += xv.w * wv.z; acc[3][3] += xv.w * wv.w;
        }
    }

#pragma unroll
    for (int i = 0; i < 4; ++i) {
        long row = row0 + ty * 4 + i;
        if (row < n) {
            float4 o = {acc[i][0], acc[i][1], acc[i][2], acc[i][3]};
            *(float4*)(H + row * 64 + tx * 4) = o;
        }
    }
    float4 asv = *(const float4*)(As + tx * 4);
    float4 adv = *(const float4*)(Ad + tx * 4);
#pragma unroll
    for (int i = 0; i < 4; ++i) {
        float ps = acc[i][0] * asv.x + acc[i][1] * asv.y + acc[i][2] * asv.z + acc[i][3] * asv.w;
        float pd = acc[i][0] * adv.x + acc[i][1] * adv.y + acc[i][2] * adv.z + acc[i][3] * adv.w;
#pragma unroll
        for (int off = 1; off < 16; off <<= 1) {
            ps += __shfl_xor(ps, off);
            pd += __shfl_xor(pd, off);
        }
        if (tx == 0) {
            long row = row0 + ty * 4 + i;
            if (row < n) { AS[row] = ps; AD[row] = pd; }
        }
    }
}

// ---------------- per-node softmax-aggregate (contiguous CSR) ----------------
__global__ __launch_bounds__(256) void k_agg(
    const int* __restrict__ rowptr, const int* __restrict__ csr,
    const float* __restrict__ AS, const float* __restrict__ AD,
    const float* __restrict__ H, const float* __restrict__ B,
    float* __restrict__ OUT, int n, int relu) {
    const int lane = threadIdx.x & 63;
    const int node = blockIdx.x * 4 + (threadIdx.x >> 6);
    if (node >= n) return;
    const int beg = rowptr[node], end = rowptr[node + 1];
    const int degI = end - beg;
    const int degT = degI + 1;  // + self-loop
    const float ad = AD[node];

    float acc = 0.f;
    if (degT <= 64) {
        const bool v = lane < degT;
        int s = (lane < degI) ? csr[beg + lane] : node;
        float a = v ? AS[s] + ad : -__builtin_inff();
        a = (a >= 0.f) ? a : NEG * a;
        float m = a;
#pragma unroll
        for (int off = 32; off; off >>= 1) m = fmaxf(m, __shfl_xor(m, off));
        float ez = v ? __expf(a - m) : 0.f;
        float z = ez;
#pragma unroll
        for (int off = 32; off; off >>= 1) z += __shfl_xor(z, off);
        float wgt = ez * (1.f / (z + 1e-16f));
        int j = 0;
        for (; j + 8 <= degT; j += 8) {
            int s0 = __shfl(s, j),     s1 = __shfl(s, j + 1);
            int s2 = __shfl(s, j + 2), s3 = __shfl(s, j + 3);
            int s4 = __shfl(s, j + 4), s5 = __shfl(s, j + 5);
            int s6 = __shfl(s, j + 6), s7 = __shfl(s, j + 7);
            float w0 = __shfl(wgt, j),     w1 = __shfl(wgt, j + 1);
            float w2 = __shfl(wgt, j + 2), w3 = __shfl(wgt, j + 3);
            float w4 = __shfl(wgt, j + 4), w5 = __shfl(wgt, j + 5);
            float w6 = __shfl(wgt, j + 6), w7 = __shfl(wgt, j + 7);
            float h0 = H[(long)s0 * 64 + lane];
            float h1 = H[(long)s1 * 64 + lane];
            float h2 = H[(long)s2 * 64 + lane];
            float h3 = H[(long)s3 * 64 + lane];
            float h4 = H[(long)s4 * 64 + lane];
            float h5 = H[(long)s5 * 64 + lane];
            float h6 = H[(long)s6 * 64 + lane];
            float h7 = H[(long)s7 * 64 + lane];
            acc += w0 * h0 + w1 * h1 + w2 * h2 + w3 * h3;
            acc += w4 * h4 + w5 * h5 + w6 * h6 + w7 * h7;
        }
        for (; j < degT; ++j) {
            int sj = __shfl(s, j);
            float wj = __shfl(wgt, j);
            acc += wj * H[(long)sj * 64 + lane];
        }
    } else {
        float m = -__builtin_inff(), z = 0.f;
        for (int p0 = 0; p0 < degT; p0 += 64) {
            int e = p0 + lane;
            bool v = e < degT;
            int s = (e < degI) ? csr[beg + e] : node;
            float a = v ? AS[s] + ad : -__builtin_inff();
            a = (a >= 0.f) ? a : NEG * a;
            float cm = a;
#pragma unroll
            for (int off = 32; off; off >>= 1) cm = fmaxf(cm, __shfl_xor(cm, off));
            float mn = fmaxf(m, cm);
            float ez = v ? __expf(a - mn) : 0.f;
#pragma unroll
            for (int off = 32; off; off >>= 1) ez += __shfl_xor(ez, off);
            z = (p0 == 0) ? ez : z * __expf(m - mn) + ez;
            m = mn;
        }
        const float invz = 1.f / (z + 1e-16f);
        for (int p0 = 0; p0 < degT; p0 += 64) {
            int e = p0 + lane;
            bool v = e < degT;
            int s = (e < degI) ? csr[beg + e] : node;
            float wgt = 0.f;
            if (v) {
                float a = AS[s] + ad;
                a = (a >= 0.f) ? a : NEG * a;
                wgt = __expf(a - m) * invz;
            }
            int cntv = min(64, degT - p0);
            for (int j = 0; j < cntv; ++j) {
                int sj = __shfl(s, j);
                float wj = __shfl(wgt, j);
                acc += wj * H[(long)sj * 64 + lane];
            }
        }
    }
    acc += B[lane];
    if (relu) acc = fmaxf(acc, 0.f);
    OUT[(long)node * 64 + lane] = acc;
}

// ---------------- launch ----------------
extern "C" void kernel_launch(void* const* d_in, const int* in_sizes, int n_in,
                              void* d_out, int out_size, void* d_ws, size_t ws_size,
                              hipStream_t stream) {
    const float* x   = (const float*)d_in[0];
    const void*  eix = d_in[1];
    const float* W1  = (const float*)d_in[2];
    const float* as1 = (const float*)d_in[3];
    const float* ad1 = (const float*)d_in[4];
    const float* b1  = (const float*)d_in[5];
    const float* W2  = (const float*)d_in[6];
    const float* as2 = (const float*)d_in[7];
    const float* ad2 = (const float*)d_in[8];
    const float* b2  = (const float*)d_in[9];
    float* out = (float*)d_out;

    const int  n  = NN;
    const long E  = (long)in_sizes[1] / 2;
    const int  NS = NX * NN;  // 800000

    // workspace carve (256B aligned bump allocator), ~52 MB total
    char* w = (char*)d_ws;
    size_t off = 0;
    auto alloc = [&](size_t bytes) -> void* {
        void* p = w + off;
        off = (off + bytes + 255) & ~(size_t)255;
        return p;
    };
    int*      mode    = (int*)alloc(4);
    int*      cnt     = (int*)alloc((size_t)NS * 4);
    int*      S       = (int*)alloc((size_t)NS * 4);
    int*      bsums   = (int*)alloc(1024 * 4);
    unsigned* combo   = (unsigned*)alloc((size_t)E * 4);
    int*      csr     = (int*)alloc((size_t)E * 4);
    int*      csr2    = (int*)alloc((size_t)E * 4);
    int*      rowptr2 = (int*)alloc((size_t)(n + 1) * 4);
    float*    H       = (float*)alloc((size_t)n * 64 * 4);
    float*    AS      = (float*)alloc((size_t)n * 4);
    float*    AD      = (float*)alloc((size_t)n * 4);

    const int nbZ  = (NS + 255) / 256;          // 3125 (zero)
    const int nbE2 = (int)((E + 511) / 512);    // 3125 (2 edges/thread)
    const int nbS  = (NS + 1023) / 1024;        // 782  (scan level-1)
    const int nbN  = (n + 255) / 256;           // 391
    const int nbG  = (n + 63) / 64;             // 1563

    k_zero_detect<<<nbZ, 256, 0, stream>>>(cnt, NS, eix, mode);
    k_count<<<nbE2, 256, 0, stream>>>(eix, E, mode, cnt, combo);
    k_scan_block<<<nbS, 1024, 0, stream>>>(cnt, S, bsums, NS);
    k_scan_mid<<<1, 1024, 0, stream>>>(bsums, nbS);
    k_scan_add<<<nbS, 1024, 0, stream>>>(S, bsums, NS);
    k_fill<<<nbE2, 256, 0, stream>>>(eix, E, mode, S, combo, csr);
    k_reorder<<<nbN, 256, 0, stream>>>(cnt, S, csr, csr2, rowptr2, E, n);

    // layer 1: h1 = x@W1 (+attn dots), aggregate + relu -> out (as temp)
    k_gemm_attn<128><<<nbG, 256, 0, stream>>>(x, W1, as1, ad1, H, AS, AD, n);
    k_agg<<<(n + 3) / 4, 256, 0, stream>>>(rowptr2, csr2, AS, AD, H, b1, out, n, 1);
    // layer 2: h2 = out@W2 (+attn dots), aggregate -> out
    k_gemm_attn<64><<<nbG, 256, 0, stream>>>(out, W2, as2, ad2, H, AS, AD, n);
    k_agg<<<(n + 3) / 4, 256, 0, stream>>>(rowptr2, csr2, AS, AD, H, b2, out, n, 0);
}

// Round 11
// 395.524 us; speedup vs baseline: 1.2001x; 1.0095x over previous
//
#include <hip/hip_runtime.h>
#include <hip/hip_fp16.h>
#include <cstdint>

#define NN 100000
#define NX 8            // CSR partitions (label = blockIdx&7 for fill locality)
#define NEG 0.2f

// ---------------- zero + edge dtype detector (fused) ----------------
__global__ void k_zero_detect(int* p, int n, const void* e, int* mode) {
    int i = blockIdx.x * 256 + threadIdx.x;
    if (i < n) p[i] = 0;
    if (blockIdx.x == 0 && threadIdx.x == 0) {
        const int* q = (const int*)e;
        int allz = 1;
        for (int j = 0; j < 64; ++j)
            if (q[2 * j + 1] != 0) { allz = 0; break; }
        mode[0] = allz;  // 1 => int64, 0 => int32
    }
}

// ---------------- partitioned CSR build ----------------
// count: atomicAdd returns this edge's RANK within cell (x,d); persist
// combo[e] = (rank<<17)|d so k_fill needs NO atomics.
__global__ void k_count(const void* e, long E, const int* mode, int* cnt,
                        unsigned* combo) {
    long i0 = ((long)blockIdx.x * 256 + threadIdx.x) * 2;
    if (i0 >= E) return;
    const int x = (int)(blockIdx.x & (NX - 1));
    const bool has1 = (i0 + 1) < E;
    int d0, d1 = 0;
    if (mode[0]) {
        const long long* p = (const long long*)e;
        d0 = (int)p[E + i0];
        if (has1) d1 = (int)p[E + i0 + 1];
    } else {
        const int* p = (const int*)e;
        d0 = p[E + i0];
        if (has1) d1 = p[E + i0 + 1];
    }
    int r0 = atomicAdd(&cnt[x * NN + d0], 1);
    combo[i0] = ((unsigned)r0 << 17) | (unsigned)d0;
    if (has1) {
        int r1 = atomicAdd(&cnt[x * NN + d1], 1);
        combo[i0 + 1] = ((unsigned)r1 << 17) | (unsigned)d1;
    }
}

// 3-level exclusive scan over NS=8*NN: level-1 blocks of 1024 -> 782 bsums.
__global__ void k_scan_block(const int* cnt, int* S, int* bsums, int n) {
    __shared__ int sm[1024];
    const int t = threadIdx.x;
    int i = blockIdx.x * 1024 + t;
    int v = (i < n) ? cnt[i] : 0;
    sm[t] = v;
    __syncthreads();
    for (int off = 1; off < 1024; off <<= 1) {
        int tv = (t >= off) ? sm[t - off] : 0;
        __syncthreads();
        sm[t] += tv;
        __syncthreads();
    }
    if (i < n) S[i] = sm[t] - v;
    if (t == 1023) bsums[blockIdx.x] = sm[1023];
}

__global__ void k_scan_mid(int* bs, int nb) {
    __shared__ int sm[1024];
    const int t = threadIdx.x;
    int v = (t < nb) ? bs[t] : 0;
    sm[t] = v;
    __syncthreads();
    for (int off = 1; off < 1024; off <<= 1) {
        int tv = (t >= off) ? sm[t - off] : 0;
        __syncthreads();
        sm[t] += tv;
        __syncthreads();
    }
    if (t < nb) bs[t] = sm[t] - v;  // exclusive
}

__global__ void k_scan_add(int* S, const int* bsums, int n) {
    int i = blockIdx.x * 1024 + threadIdx.x;
    if (i < n) S[i] += bsums[blockIdx.x];
}

// fill: slot = S[x*NN+d] + rank (from combo) — NO atomics. S stays pristine.
__global__ void k_fill(const void* e, long E, const int* mode, const int* S,
                       const unsigned* combo, int* csr) {
    long i0 = ((long)blockIdx.x * 256 + threadIdx.x) * 2;
    if (i0 >= E) return;
    const int x = (int)(blockIdx.x & (NX - 1));
    const bool has1 = (i0 + 1) < E;
    long s0, s1 = 0;
    if (mode[0]) {
        const long long* p = (const long long*)e;
        s0 = p[i0];
        if (has1) s1 = p[i0 + 1];
    } else {
        const int* p = (const int*)e;
        s0 = p[i0];
        if (has1) s1 = p[i0 + 1];
    }
    unsigned c0 = combo[i0];
    int d0 = (int)(c0 & 0x1FFFFu), r0 = (int)(c0 >> 17);
    csr[S[x * NN + d0] + r0] = (int)s0;
    if (has1) {
        unsigned c1 = combo[i0 + 1];
        int d1 = (int)(c1 & 0x1FFFFu), r1 = (int)(c1 >> 17);
        csr[S[x * NN + d1] + r1] = (int)s1;
    }
}

// ---------------- reorder: x-major csr -> node-contiguous csr2 ----------------
__global__ void k_reorder(const int* cnt, const int* S, const int* csr,
                          int* csr2, int* rowptr2, long E, int n) {
    int d = blockIdx.x * 256 + threadIdx.x;
    if (d >= n) return;
    int C = 0, sum = 0;
    int st[NX], cx[NX];
#pragma unroll
    for (int x = 0; x < NX; ++x) {
        C += S[(long)x * NN];
        st[x] = S[(long)x * NN + d];
        cx[x] = cnt[(long)x * NN + d];
        sum += st[x];
    }
    int start = sum - C;
    rowptr2[d] = start;
    if (d == 0) rowptr2[n] = (int)E;
#pragma unroll
    for (int x = 0; x < NX; ++x) {
        int c = cx[x], s0 = st[x];
        for (int j = 0; j < c; ++j) csr2[start++] = csr[s0 + j];
    }
}

// ---------------- register-tiled GEMM + attention dots ----------------
// H stored FP16 (gather payload halved); AS/AD stay fp32 from fp32 acc.
template <int K>
__global__ __launch_bounds__(256) void k_gemm_attn(
    const float* __restrict__ X, const float* __restrict__ W,
    const float* __restrict__ As, const float* __restrict__ Ad,
    __half* __restrict__ H, float* __restrict__ AS, float* __restrict__ AD, int n) {
    constexpr int KC = 32;
    __shared__ float Wl[KC * 64];   // 8 KB
    __shared__ float Xt[KC][68];    // 8.5 KB, transposed [k][row]
    const int tid = threadIdx.x;
    const int tx = tid & 15, ty = tid >> 4;
    const long row0 = (long)blockIdx.x * 64;
    float acc[4][4] = {{0.f}};

    for (int k0 = 0; k0 < K; k0 += KC) {
        __syncthreads();
        {
            const float4* src = (const float4*)(W + (long)k0 * 64);
            float4* dst = (float4*)Wl;
            for (int i = tid; i < KC * 64 / 4; i += 256) dst[i] = src[i];
        }
        {
            const int rr = tid >> 3;   // 0..31
            const int kq = tid & 7;    // k sub-offset kq*4
#pragma unroll
            for (int h = 0; h < 2; ++h) {
                int r = rr + h * 32;
                long row = row0 + r;
                if (row >= n) row = n - 1;
                float4 v = *(const float4*)(X + row * K + k0 + kq * 4);
                Xt[kq * 4 + 0][r] = v.x;
                Xt[kq * 4 + 1][r] = v.y;
                Xt[kq * 4 + 2][r] = v.z;
                Xt[kq * 4 + 3][r] = v.w;
            }
        }
        __syncthreads();
#pragma unroll
        for (int kk = 0; kk < KC; ++kk) {
            float4 xv = *(const float4*)(&Xt[kk][ty * 4]);
            float4 wv = *(const float4*)(&Wl[kk * 64 + tx * 4]);
            acc[0][0] += xv.x * wv.x; acc[0][1] += xv.x * wv.y;
            acc[0][2] += xv.x * wv.z; acc[0][3] += xv.x * wv.w;
            acc[1][0] += xv.y * wv.x; acc[1][1] += xv.y * wv.y;
            acc[1][2] += xv.y * wv.z; acc[1][3] += xv.y * wv.w;
            acc[2][0] += xv.z * wv.x; acc[2][1] += xv.z * wv.y;
            acc[2][2] += xv.z * wv.z; acc[2][3] += xv.z * wv.w;
            acc[3][0] += xv.w * wv.x; acc[3][1] += xv.w * wv.y;
            acc[3][2] += xv.w * wv.z; acc[3][3] += xv.w * wv.w;
        }
    }

#pragma unroll
    for (int i = 0; i < 4; ++i) {
        long row = row0 + ty * 4 + i;
        if (row < n) {
            __half2 p0 = __floats2half2_rn(acc[i][0], acc[i][1]);
            __half2 p1 = __floats2half2_rn(acc[i][2], acc[i][3]);
            __half2* hp = (__half2*)(H + row * 64 + tx * 4);
            hp[0] = p0;
            hp[1] = p1;
        }
    }
    float4 asv = *(const float4*)(As + tx * 4);
    float4 adv = *(const float4*)(Ad + tx * 4);
#pragma unroll
    for (int i = 0; i < 4; ++i) {
        float ps = acc[i][0] * asv.x + acc[i][1] * asv.y + acc[i][2] * asv.z + acc[i][3] * asv.w;
        float pd = acc[i][0] * adv.x + acc[i][1] * adv.y + acc[i][2] * adv.z + acc[i][3] * adv.w;
#pragma unroll
        for (int off = 1; off < 16; off <<= 1) {
            ps += __shfl_xor(ps, off);
            pd += __shfl_xor(pd, off);
        }
        if (tx == 0) {
            long row = row0 + ty * 4 + i;
            if (row < n) { AS[row] = ps; AD[row] = pd; }
        }
    }
}

// ---------------- per-node softmax-aggregate (contiguous CSR, fp16 H) --------
__global__ __launch_bounds__(256) void k_agg(
    const int* __restrict__ rowptr, const int* __restrict__ csr,
    const float* __restrict__ AS, const float* __restrict__ AD,
    const __half* __restrict__ H, const float* __restrict__ B,
    float* __restrict__ OUT, int n, int relu) {
    const int lane = threadIdx.x & 63;
    const int node = blockIdx.x * 4 + (threadIdx.x >> 6);
    if (node >= n) return;
    const int beg = rowptr[node], end = rowptr[node + 1];
    const int degI = end - beg;
    const int degT = degI + 1;  // + self-loop
    const float ad = AD[node];

    float acc = 0.f;
    if (degT <= 64) {
        const bool v = lane < degT;
        int s = (lane < degI) ? csr[beg + lane] : node;
        float a = v ? AS[s] + ad : -__builtin_inff();
        a = (a >= 0.f) ? a : NEG * a;
        float m = a;
#pragma unroll
        for (int off = 32; off; off >>= 1) m = fmaxf(m, __shfl_xor(m, off));
        float ez = v ? __expf(a - m) : 0.f;
        float z = ez;
#pragma unroll
        for (int off = 32; off; off >>= 1) z += __shfl_xor(z, off);
        float wgt = ez * (1.f / (z + 1e-16f));
        int j = 0;
        for (; j + 8 <= degT; j += 8) {
            int s0 = __shfl(s, j),     s1 = __shfl(s, j + 1);
            int s2 = __shfl(s, j + 2), s3 = __shfl(s, j + 3);
            int s4 = __shfl(s, j + 4), s5 = __shfl(s, j + 5);
            int s6 = __shfl(s, j + 6), s7 = __shfl(s, j + 7);
            float w0 = __shfl(wgt, j),     w1 = __shfl(wgt, j + 1);
            float w2 = __shfl(wgt, j + 2), w3 = __shfl(wgt, j + 3);
            float w4 = __shfl(wgt, j + 4), w5 = __shfl(wgt, j + 5);
            float w6 = __shfl(wgt, j + 6), w7 = __shfl(wgt, j + 7);
            float h0 = __half2float(H[(long)s0 * 64 + lane]);
            float h1 = __half2float(H[(long)s1 * 64 + lane]);
            float h2 = __half2float(H[(long)s2 * 64 + lane]);
            float h3 = __half2float(H[(long)s3 * 64 + lane]);
            float h4 = __half2float(H[(long)s4 * 64 + lane]);
            float h5 = __half2float(H[(long)s5 * 64 + lane]);
            float h6 = __half2float(H[(long)s6 * 64 + lane]);
            float h7 = __half2float(H[(long)s7 * 64 + lane]);
            acc += w0 * h0 + w1 * h1 + w2 * h2 + w3 * h3;
            acc += w4 * h4 + w5 * h5 + w6 * h6 + w7 * h7;
        }
        for (; j < degT; ++j) {
            int sj = __shfl(s, j);
            float wj = __shfl(wgt, j);
            acc += wj * __half2float(H[(long)sj * 64 + lane]);
        }
    } else {
        float m = -__builtin_inff(), z = 0.f;
        for (int p0 = 0; p0 < degT; p0 += 64) {
            int e = p0 + lane;
            bool v = e < degT;
            int s = (e < degI) ? csr[beg + e] : node;
            float a = v ? AS[s] + ad : -__builtin_inff();
            a = (a >= 0.f) ? a : NEG * a;
            float cm = a;
#pragma unroll
            for (int off = 32; off; off >>= 1) cm = fmaxf(cm, __shfl_xor(cm, off));
            float mn = fmaxf(m, cm);
            float ez = v ? __expf(a - mn) : 0.f;
#pragma unroll
            for (int off = 32; off; off >>= 1) ez += __shfl_xor(ez, off);
            z = (p0 == 0) ? ez : z * __expf(m - mn) + ez;
            m = mn;
        }
        const float invz = 1.f / (z + 1e-16f);
        for (int p0 = 0; p0 < degT; p0 += 64) {
            int e = p0 + lane;
            bool v = e < degT;
            int s = (e < degI) ? csr[beg + e] : node;
            float wgt = 0.f;
            if (v) {
                float a = AS[s] + ad;
                a = (a >= 0.f) ? a : NEG * a;
                wgt = __expf(a - m) * invz;
            }
            int cntv = min(64, degT - p0);
            for (int j = 0; j < cntv; ++j) {
                int sj = __shfl(s, j);
                float wj = __shfl(wgt, j);
                acc += wj * __half2float(H[(long)sj * 64 + lane]);
            }
        }
    }
    acc += B[lane];
    if (relu) acc = fmaxf(acc, 0.f);
    OUT[(long)node * 64 + lane] = acc;
}

// ---------------- launch ----------------
extern "C" void kernel_launch(void* const* d_in, const int* in_sizes, int n_in,
                              void* d_out, int out_size, void* d_ws, size_t ws_size,
                              hipStream_t stream) {
    const float* x   = (const float*)d_in[0];
    const void*  eix = d_in[1];
    const float* W1  = (const float*)d_in[2];
    const float* as1 = (const float*)d_in[3];
    const float* ad1 = (const float*)d_in[4];
    const float* b1  = (const float*)d_in[5];
    const float* W2  = (const float*)d_in[6];
    const float* as2 = (const float*)d_in[7];
    const float* ad2 = (const float*)d_in[8];
    const float* b2  = (const float*)d_in[9];
    float* out = (float*)d_out;

    const int  n  = NN;
    const long E  = (long)in_sizes[1] / 2;
    const int  NS = NX * NN;  // 800000

    // workspace carve (256B aligned bump allocator), ~40 MB total
    char* w = (char*)d_ws;
    size_t off = 0;
    auto alloc = [&](size_t bytes) -> void* {
        void* p = w + off;
        off = (off + bytes + 255) & ~(size_t)255;
        return p;
    };
    int*      mode    = (int*)alloc(4);
    int*      cnt     = (int*)alloc((size_t)NS * 4);
    int*      S       = (int*)alloc((size_t)NS * 4);
    int*      bsums   = (int*)alloc(1024 * 4);
    unsigned* combo   = (unsigned*)alloc((size_t)E * 4);
    int*      csr     = (int*)alloc((size_t)E * 4);
    int*      csr2    = (int*)alloc((size_t)E * 4);
    int*      rowptr2 = (int*)alloc((size_t)(n + 1) * 4);
    __half*   H       = (__half*)alloc((size_t)n * 64 * 2);
    float*    AS      = (float*)alloc((size_t)n * 4);
    float*    AD      = (float*)alloc((size_t)n * 4);

    const int nbZ  = (NS + 255) / 256;          // 3125 (zero)
    const int nbE2 = (int)((E + 511) / 512);    // 3125 (2 edges/thread)
    const int nbS  = (NS + 1023) / 1024;        // 782  (scan level-1)
    const int nbN  = (n + 255) / 256;           // 391
    const int nbG  = (n + 63) / 64;             // 1563

    k_zero_detect<<<nbZ, 256, 0, stream>>>(cnt, NS, eix, mode);
    k_count<<<nbE2, 256, 0, stream>>>(eix, E, mode, cnt, combo);
    k_scan_block<<<nbS, 1024, 0, stream>>>(cnt, S, bsums, NS);
    k_scan_mid<<<1, 1024, 0, stream>>>(bsums, nbS);
    k_scan_add<<<nbS, 1024, 0, stream>>>(S, bsums, NS);
    k_fill<<<nbE2, 256, 0, stream>>>(eix, E, mode, S, combo, csr);
    k_reorder<<<nbN, 256, 0, stream>>>(cnt, S, csr, csr2, rowptr2, E, n);

    // layer 1: h1 = x@W1 (+attn dots), aggregate + relu -> out (as temp)
    k_gemm_attn<128><<<nbG, 256, 0, stream>>>(x, W1, as1, ad1, H, AS, AD, n);
    k_agg<<<(n + 3) / 4, 256, 0, stream>>>(rowptr2, csr2, AS, AD, H, b1, out, n, 1);
    // layer 2: h2 = out@W2 (+attn dots), aggregate -> out
    k_gemm_attn<64><<<nbG, 256, 0, stream>>>(out, W2, as2, ad2, H, AS, AD, n);
    k_agg<<<(n + 3) / 4, 256, 0, stream>>>(rowptr2, csr2, AS, AD, H, b2, out, n, 0);
}